// Round 2
// baseline (112.422 us; speedup 1.0000x reference)
//
#include <hip/hip_runtime.h>
#include <hip/hip_bf16.h>

// Shapes (hard-coded): B=16, Wn=64, K=256, E=128, O=64
// x:(16,64,256) lin_w:(128,128) lin_b:(128) a:(128) bias_kk:(256,256)
// fc_w:(64,256) fc_b:(64)  out:(16,64,64) fp32
//
// Tuning history (MI355X):
//  R5: cooperative-kernel fusion regressed 106->233 us. Keep 3 dispatches.
//  R6->R7: XCD swizzle (blk&7 = XCD owns b pair for producer+consumers);
//      best = 104.3 us.
//  R8: i-tile 8->4 + 1024 blocks REGRESSED (duplicated right/v traffic).
//  R9: k_attn latency fixes (r-row reg hoist, v via global_load_lds drained
//      at b2, barriers 7->3). k_attn 41.6 -> <40.4 us but dur_us ~flat
//      (108.4, jitter) -- still ~6x above VALU floor; occupancy pinned at
//      2 waves/SIMD was the structural limit.
//  R10 (this round): TLP x2 at constant traffic. k_attn: 512-thread blocks,
//      same 512-block grid. e-dim split across adjacent lane pairs
//      (j=tid>>1, eh=tid&1; r-hoist 16 float4/thread; one shfl_xor combine).
//      PV pairs lanes over j-halves. Wave wv reduces AND consumes softmax
//      row wv -> inv stays in registers. launch_bounds(512,4) caps VGPR at
//      128 so 2 blocks/CU co-reside (16 waves/CU = 4/SIMD). bk loads moved
//      to just before b2 to stay under the cap.
//  dur_us includes ~41.6 us harness poison fill (268 MB) per iteration.
#define ALPHA 0.2f
#define C1 0.6f   // (1+ALPHA)/2
#define C2 0.4f   // (1-ALPHA)/2

typedef const __attribute__((address_space(1))) float gas_float;
typedef __attribute__((address_space(3))) float las_float;

__device__ __forceinline__ void gld_lds16(const float* g, float* l) {
  // global -> LDS DMA, 16B per lane; LDS dest = wave-uniform base + lane*16.
  __builtin_amdgcn_global_load_lds((gas_float*)g, (las_float*)l, 16, 0, 0);
}

// ---------------- Kernel A: left/right projections + v transpose ----------
// grid = B * (K/8) = 512 blocks (2/CU), 256 threads. Tile of 8 k's per block.
// XCD swizzle: x = blk&7, s = blk>>3; b = 2x + (s&1), k0 = (s>>1)*8.
__global__ __launch_bounds__(256) void k_proj(
    const float* __restrict__ x, const float* __restrict__ lin_w,
    float* __restrict__ left, float* __restrict__ right, float* __restrict__ v) {
  const int xcd = blockIdx.x & 7;
  const int s   = blockIdx.x >> 3;
  const int b   = 2 * xcd + (s & 1);
  const int k0  = (s >> 1) * 8;
  const int tid = threadIdx.x;

  __shared__ float s_x[8][68];  // [k][w]

  // load x[b, w, k0:k0+8] -> s_x[k][w] (transpose). float2 over k.
  {
    const int w  = tid >> 2;      // 0..63
    const int kq = tid & 3;       // 0..3
    float2 xv = *(const float2*)(x + b * 16384 + w * 256 + k0 + kq * 2);
    s_x[kq * 2 + 0][w] = xv.x;
    s_x[kq * 2 + 1][w] = xv.y;
  }
  __syncthreads();

  // write v[b, k, w] (coalesced float4), threads 0..127
  if (tid < 128) {
    const int k  = tid >> 4;      // 0..7
    const int wq = tid & 15;      // 0..15
    float4 vv = *(const float4*)&s_x[k][wq * 4];
    *(float4*)(v + (b * 256 + k0 + k) * 64 + wq * 4) = vv;
  }

  // compute left/right: thread = (e = tid&127, kh = tid>>7); 4 k's each.
  const int e  = tid & 127;
  const int kh = tid >> 7;  // 0..1
  float accL[4] = {0, 0, 0, 0};
  float accR[4] = {0, 0, 0, 0};
  const float4* w1 = (const float4*)(lin_w + e * 128);       // W1 row e
  const float4* w2 = w1 + 16;                                // W2 row e
#pragma unroll
  for (int wc = 0; wc < 16; ++wc) {
    float4 l = w1[wc];
    float4 r = w2[wc];
#pragma unroll
    for (int k = 0; k < 4; ++k) {
      float4 sx = *(const float4*)&s_x[kh * 4 + k][wc * 4];  // broadcast
      accL[k] += sx.x * l.x + sx.y * l.y + sx.z * l.z + sx.w * l.w;
      accR[k] += sx.x * r.x + sx.y * r.y + sx.z * r.z + sx.w * r.w;
    }
  }
#pragma unroll
  for (int k = 0; k < 4; ++k) {
    int kk = (b * 256 + k0 + kh * 4 + k) * 128 + e;
    left[kk]  = accL[k];
    right[kk] = accR[k];
  }
}

// ---------------- Kernel B: scores + softmax + attn*v + sigmoid -----------
// grid = 512 blocks x 512 threads (2 blocks/CU, 4 waves/SIMD). XCD swizzle
// matches k_proj: x = blk&7, s = blk>>3; b = 2x + (s&1), i0 = (s>>1)*8.
// Score phase: thread = (j = tid>>1, eh = tid&1); each computes the e-half
// dot; adjacent-lane shfl_xor(1) combines. Softmax WITHOUT max-subtraction
// (scores O(+-5), fp32-safe, absmax ~1e-3 since R4).
__global__ __launch_bounds__(512, 4) void k_attn(
    const float* __restrict__ left, const float* __restrict__ right,
    const float* __restrict__ lin_b, const float* __restrict__ a,
    const float* __restrict__ bias_kk, const float* __restrict__ v,
    float* __restrict__ h) {
  const int xcd  = blockIdx.x & 7;
  const int sblk = blockIdx.x >> 3;
  const int b    = 2 * xcd + (sblk & 1);
  const int i0   = (sblk >> 1) * 8;
  const int tid  = threadIdx.x;
  const int j    = tid >> 1;    // 0..255 (score-row owner pair)
  const int eh   = tid & 1;     // e-half: [0,64) or [64,128)

  __shared__ float s_lb[8][132];    // left[b,i0+i,:] + lin_b
  __shared__ float s_a[128];
  __shared__ float s_ca[128];       // C2 * a
  __shared__ float s_AL[8];
  __shared__ float s_sc[8][260];    // exp(score) (unnormalized p)
  __shared__ float s_v[256][64];    // full v[b] panel, linear (DMA target)

  // ---- stage a / 0.4*a and left-tile (+lin_b) ----
  if (tid < 128) {
    float av = a[tid];
    s_a[tid]  = av;
    s_ca[tid] = C2 * av;
  }
  {
    const int ii = tid >> 6;          // 0..7
    const int e2 = (tid & 63) * 2;
    float2 lv = *(const float2*)(left + (b * 256 + i0 + ii) * 128 + e2);
    float2 bv = *(const float2*)(lin_b + e2);
    s_lb[ii][e2 + 0] = lv.x + bv.x;
    s_lb[ii][e2 + 1] = lv.y + bv.y;
  }
  __syncthreads();  // b1

  // ---- hoist this thread's e-half of right row j: 16 b128 loads ----
  const float4* rp = (const float4*)(right + (b * 256 + j) * 128 + eh * 64);
  float4 r[16];
#pragma unroll
  for (int q = 0; q < 16; ++q) r[q] = rp[q];

  // ---- async-stage v[b] (256x64 = 64KB) into LDS; drains at b2 ----
  {
    const int seg0 = (tid >> 6) * 8;      // wave's 8 segments (256 floats ea)
    const int ln4  = (tid & 63) * 4;
    const float* vb = v + b * 16384;
#pragma unroll
    for (int t = 0; t < 8; ++t) {
      const int seg = seg0 + t;
      gld_lds16(vb + seg * 256 + ln4, &s_v[0][0] + seg * 256);
    }
  }

  // ---- AL[i] = sum_e a_e * lb[i][e]: wave wv reduces row wv ----
  {
    const int ii = tid >> 6, sl = tid & 63;
    float p = s_a[sl * 2] * s_lb[ii][sl * 2] +
              s_a[sl * 2 + 1] * s_lb[ii][sl * 2 + 1];
#pragma unroll
    for (int off = 32; off > 0; off >>= 1) p += __shfl_xor(p, off, 64);
    if (sl == 0) s_AL[ii] = p;
  }

  // ---- scores (half-row): acc[i] += 0.4a|lb+r|, ar += a*r over 64 e's ----
  float acc[8];
#pragma unroll
  for (int i = 0; i < 8; ++i) acc[i] = 0.f;
  float ar = 0.f;
  const int eb = eh * 64;
#pragma unroll
  for (int ec = 0; ec < 4; ++ec) {
    float4 r0 = r[ec * 4 + 0], r1 = r[ec * 4 + 1],
           r2 = r[ec * 4 + 2], r3 = r[ec * 4 + 3];
    const int base = eb + ec * 16;
    float4 a0 = *(const float4*)&s_a[base + 0];
    float4 a1 = *(const float4*)&s_a[base + 4];
    float4 a2 = *(const float4*)&s_a[base + 8];
    float4 a3 = *(const float4*)&s_a[base + 12];
    ar += a0.x * r0.x + a0.y * r0.y + a0.z * r0.z + a0.w * r0.w;
    ar += a1.x * r1.x + a1.y * r1.y + a1.z * r1.z + a1.w * r1.w;
    ar += a2.x * r2.x + a2.y * r2.y + a2.z * r2.z + a2.w * r2.w;
    ar += a3.x * r3.x + a3.y * r3.y + a3.z * r3.z + a3.w * r3.w;
    float4 c0 = *(const float4*)&s_ca[base + 0];
    float4 c1 = *(const float4*)&s_ca[base + 4];
    float4 c2 = *(const float4*)&s_ca[base + 8];
    float4 c3 = *(const float4*)&s_ca[base + 12];
#pragma unroll
    for (int i = 0; i < 8; ++i) {
      float4 l0 = *(const float4*)&s_lb[i][base + 0];
      float4 l1 = *(const float4*)&s_lb[i][base + 4];
      float4 l2 = *(const float4*)&s_lb[i][base + 8];
      float4 l3 = *(const float4*)&s_lb[i][base + 12];
      float t, s = acc[i];
      t = l0.x + r0.x; s = fmaf(c0.x, fabsf(t), s);
      t = l0.y + r0.y; s = fmaf(c0.y, fabsf(t), s);
      t = l0.z + r0.z; s = fmaf(c0.z, fabsf(t), s);
      t = l0.w + r0.w; s = fmaf(c0.w, fabsf(t), s);
      t = l1.x + r1.x; s = fmaf(c1.x, fabsf(t), s);
      t = l1.y + r1.y; s = fmaf(c1.y, fabsf(t), s);
      t = l1.z + r1.z; s = fmaf(c1.z, fabsf(t), s);
      t = l1.w + r1.w; s = fmaf(c1.w, fabsf(t), s);
      t = l2.x + r2.x; s = fmaf(c2.x, fabsf(t), s);
      t = l2.y + r2.y; s = fmaf(c2.y, fabsf(t), s);
      t = l2.z + r2.z; s = fmaf(c2.z, fabsf(t), s);
      t = l2.w + r2.w; s = fmaf(c2.w, fabsf(t), s);
      t = l3.x + r3.x; s = fmaf(c3.x, fabsf(t), s);
      t = l3.y + r3.y; s = fmaf(c3.y, fabsf(t), s);
      t = l3.z + r3.z; s = fmaf(c3.z, fabsf(t), s);
      t = l3.w + r3.w; s = fmaf(c3.w, fabsf(t), s);
      acc[i] = s;
    }
  }

  // ---- bias row loads (issued late: not live across score loop; latency
  //      hidden under the b2 barrier wait) ----
  float bk[8];
#pragma unroll
  for (int i = 0; i < 8; ++i) bk[i] = bias_kk[(i0 + i) * 256 + j];

  __syncthreads();  // b2 (s_AL visible; v DMA drained by implicit vmcnt(0))

  // ---- combine e-halves across the lane pair ----
#pragma unroll
  for (int i = 0; i < 8; ++i) acc[i] += __shfl_xor(acc[i], 1, 64);
  ar += __shfl_xor(ar, 1, 64);

  // ---- finalize + exp, even lane of each pair writes p ----
#pragma unroll
  for (int i = 0; i < 8; ++i) {
    float sc = fmaf(C1, s_AL[i] + ar, acc[i]) + bk[i];
    float p = __expf(sc);
    if (eh == 0) s_sc[i][j] = p;
  }
  __syncthreads();  // b3

  // ---- row sum: wave wv reduces row wv (the row it consumes in PV);
  //      64-lane butterfly leaves 1/sum in every lane's register ----
  float inv;
  {
    const int wv = tid >> 6, lane = tid & 63;
    float ssum = s_sc[wv][lane] + s_sc[wv][lane + 64] +
                 s_sc[wv][lane + 128] + s_sc[wv][lane + 192];
#pragma unroll
    for (int off = 32; off > 0; off >>= 1) ssum += __shfl_xor(ssum, off, 64);
    inv = 1.f / ssum;
  }

  // ---- h[i,w] = sigmoid( (sum_j p_j * v[j,w]) * inv ), all from LDS.
  //      Pair split over j-halves: q = tid>>1 -> (iq = q>>5, wp = q&31),
  //      jh = tid&1 covers j in [jh*128, jh*128+128). ----
  const int iq = tid >> 6;              // == wave id == row
  const int wp = (tid >> 1) & 31;
  const int jh = tid & 1;
  const int w  = wp * 2;
  float h0 = 0.f, h1 = 0.f;
  const int jbase = jh * 128;
#pragma unroll 4
  for (int jj = 0; jj < 128; jj += 4) {
    float4 at = *(const float4*)&s_sc[iq][jbase + jj];
    float2 v0 = *(const float2*)&s_v[jbase + jj + 0][w];
    float2 v1 = *(const float2*)&s_v[jbase + jj + 1][w];
    float2 v2 = *(const float2*)&s_v[jbase + jj + 2][w];
    float2 v3 = *(const float2*)&s_v[jbase + jj + 3][w];
    h0 += at.x * v0.x + at.y * v1.x + at.z * v2.x + at.w * v3.x;
    h1 += at.x * v0.y + at.y * v1.y + at.z * v2.y + at.w * v3.y;
  }
  h0 += __shfl_xor(h0, 1, 64);
  h1 += __shfl_xor(h1, 1, 64);
  if (jh == 0) {
    float2 hv;
    hv.x = 1.f / (1.f + __expf(-h0 * inv));
    hv.y = 1.f / (1.f + __expf(-h1 * inv));
    *(float2*)(h + (b * 256 + i0 + iq) * 64 + w) = hv;
  }
}

// ---------------- Kernel C: out[b,w,o] = sum_k h[b,k,w]*fc_w[o,k] + fc_b --
// grid = 256 blocks, 256 threads. XCD swizzle: x = blk&7, s = blk>>3 (0..31);
// b = 2x + (s&1), wg = s>>1 -> h[b] consumed on the XCD that produced it.
__global__ __launch_bounds__(256) void k_out(
    const float* __restrict__ h, const float* __restrict__ fc_w,
    const float* __restrict__ fc_b, float* __restrict__ out) {
  const int xcd = blockIdx.x & 7;
  const int s   = blockIdx.x >> 3;
  const int b   = 2 * xcd + (s & 1);
  const int wg  = s >> 1;        // group of 4 w's
  const int wl  = threadIdx.x >> 6;
  const int o   = threadIdx.x & 63;
  const int w   = wg * 4 + wl;

  __shared__ float s_h[256 * 4];  // [k][wl]
  for (int idx = threadIdx.x; idx < 1024; idx += 256) {
    int k = idx >> 2, wl2 = idx & 3;
    s_h[idx] = h[(b * 256 + k) * 64 + wg * 4 + wl2];
  }
  __syncthreads();

  float acc = 0.f;
  const float4* fw = (const float4*)(fc_w + o * 256);
#pragma unroll
  for (int k4 = 0; k4 < 64; ++k4) {
    float4 f = fw[k4];
    int k = k4 * 4;
    acc += s_h[(k + 0) * 4 + wl] * f.x + s_h[(k + 1) * 4 + wl] * f.y +
           s_h[(k + 2) * 4 + wl] * f.z + s_h[(k + 3) * 4 + wl] * f.w;
  }
  out[b * 64 * 64 + w * 64 + o] = acc + fc_b[o];
}

extern "C" void kernel_launch(void* const* d_in, const int* in_sizes, int n_in,
                              void* d_out, int out_size, void* d_ws, size_t ws_size,
                              hipStream_t stream) {
  const float* x       = (const float*)d_in[0];
  const float* lin_w   = (const float*)d_in[1];
  const float* lin_b   = (const float*)d_in[2];
  const float* a       = (const float*)d_in[3];
  const float* bias_kk = (const float*)d_in[4];
  const float* fc_w    = (const float*)d_in[5];
  const float* fc_b    = (const float*)d_in[6];
  float* out = (float*)d_out;

  float* ws    = (float*)d_ws;
  float* left  = ws;                // 16*256*128 = 524288
  float* right = ws + 524288;       // 524288
  float* v     = ws + 1048576;      // 16*256*64 = 262144
  float* h     = ws + 1310720;      // 262144

  k_proj<<<512, 256, 0, stream>>>(x, lin_w, left, right, v);
  k_attn<<<512, 512, 0, stream>>>(left, right, lin_b, a, bias_kk, v, h);
  k_out<<<256, 256, 0, stream>>>(h, fc_w, fc_b, out);
}

// Round 3
// 104.639 us; speedup vs baseline: 1.0744x; 1.0744x over previous
//
#include <hip/hip_runtime.h>
#include <hip/hip_bf16.h>

// Shapes (hard-coded): B=16, Wn=64, K=256, E=128, O=64
// x:(16,64,256) lin_w:(128,128) lin_b:(128) a:(128) bias_kk:(256,256)
// fc_w:(64,256) fc_b:(64)  out:(16,64,64) fp32
//
// Tuning history (MI355X):
//  R5: cooperative-kernel fusion regressed 106->233 us. Keep multi-dispatch.
//  R6->R7: XCD swizzle (blk&7 = XCD owns b pair producer+consumer); 104.3.
//  R8: i-tile 8->4 + 1024 blocks REGRESSED (duplicated right/v traffic).
//  R9: k_attn latency fixes (r-row reg hoist, v via global_load_lds drained
//      at b2, barriers 7->3). k_attn dropped below fill cutoff (<40.4).
//  R10: TLP x2 (512-thr blocks, e-split lane pairs, launch_bounds(512,4)).
//      k_attn <39.8. dur_us 104->108->112 across rounds is within the
//      container jitter of the fill-dominated wall (fills vary 39.8-41.7).
//  R11 (this round): dispatch-count reduction. k_out FUSED into k_attn:
//      each block's 8 h-rows contribute partial out[b,w,o] via atomicAdd
//      (32 adds/element, reorder noise ~1e-6 << 1e-3 tolerance); out is
//      pre-initialized to fc_b by 16 spare k_proj blocks per b. fc_w tile
//      loads issued pre-PV (latency hidden); s_h/s_fw overlay dead s_lb.
//      If dur does NOT drop, the harness reset floor (~85-90 us of 268 MB
//      poison fills) is confirmed as the wall -> ROOFLINE.
#define ALPHA 0.2f
#define C1 0.6f   // (1+ALPHA)/2
#define C2 0.4f   // (1-ALPHA)/2

typedef const __attribute__((address_space(1))) float gas_float;
typedef __attribute__((address_space(3))) float las_float;

__device__ __forceinline__ void gld_lds16(const float* g, float* l) {
  // global -> LDS DMA, 16B per lane; LDS dest = wave-uniform base + lane*16.
  __builtin_amdgcn_global_load_lds((gas_float*)g, (las_float*)l, 16, 0, 0);
}

// ---------------- Kernel A: projections + v transpose + out-init ----------
// grid = B * (K/8) = 512 blocks (2/CU), 256 threads. Tile of 8 k's per block.
// XCD swizzle: x = blk&7, s = blk>>3; b = 2x + (s&1), k0 = (s>>1)*8.
// Blocks with (s>>1) < 16 also initialize out[b] = fc_b (consumed by the
// fused k_attn's atomics; stream order guarantees no race).
__global__ __launch_bounds__(256) void k_proj(
    const float* __restrict__ x, const float* __restrict__ lin_w,
    const float* __restrict__ fc_b,
    float* __restrict__ left, float* __restrict__ right,
    float* __restrict__ v, float* __restrict__ out) {
  const int xcd = blockIdx.x & 7;
  const int s   = blockIdx.x >> 3;
  const int b   = 2 * xcd + (s & 1);
  const int k0  = (s >> 1) * 8;
  const int tid = threadIdx.x;

  __shared__ float s_x[8][68];  // [k][w]

  // out-init: 16 blocks per b cover 4096 elements, 256 each. Coalesced.
  if ((s >> 1) < 16) {
    const int idx = (s >> 1) * 256 + tid;          // = w*64 + o
    out[b * 4096 + idx] = fc_b[idx & 63];
  }

  // load x[b, w, k0:k0+8] -> s_x[k][w] (transpose). float2 over k.
  {
    const int w  = tid >> 2;      // 0..63
    const int kq = tid & 3;       // 0..3
    float2 xv = *(const float2*)(x + b * 16384 + w * 256 + k0 + kq * 2);
    s_x[kq * 2 + 0][w] = xv.x;
    s_x[kq * 2 + 1][w] = xv.y;
  }
  __syncthreads();

  // write v[b, k, w] (coalesced float4), threads 0..127
  if (tid < 128) {
    const int k  = tid >> 4;      // 0..7
    const int wq = tid & 15;      // 0..15
    float4 vv = *(const float4*)&s_x[k][wq * 4];
    *(float4*)(v + (b * 256 + k0 + k) * 64 + wq * 4) = vv;
  }

  // compute left/right: thread = (e = tid&127, kh = tid>>7); 4 k's each.
  const int e  = tid & 127;
  const int kh = tid >> 7;  // 0..1
  float accL[4] = {0, 0, 0, 0};
  float accR[4] = {0, 0, 0, 0};
  const float4* w1 = (const float4*)(lin_w + e * 128);       // W1 row e
  const float4* w2 = w1 + 16;                                // W2 row e
#pragma unroll
  for (int wc = 0; wc < 16; ++wc) {
    float4 l = w1[wc];
    float4 r = w2[wc];
#pragma unroll
    for (int k = 0; k < 4; ++k) {
      float4 sx = *(const float4*)&s_x[kh * 4 + k][wc * 4];  // broadcast
      accL[k] += sx.x * l.x + sx.y * l.y + sx.z * l.z + sx.w * l.w;
      accR[k] += sx.x * r.x + sx.y * r.y + sx.z * r.z + sx.w * r.w;
    }
  }
#pragma unroll
  for (int k = 0; k < 4; ++k) {
    int kk = (b * 256 + k0 + kh * 4 + k) * 128 + e;
    left[kk]  = accL[k];
    right[kk] = accR[k];
  }
}

// ------- Kernel B: scores + softmax + attn*v + sigmoid + fused out --------
// grid = 512 blocks x 512 threads (2 blocks/CU, 4 waves/SIMD). XCD swizzle
// matches k_proj: x = blk&7, s = blk>>3; b = 2x + (s&1), i0 = (s>>1)*8.
// Score phase: thread = (j = tid>>1, eh = tid&1); each computes the e-half
// dot; adjacent-lane shfl_xor(1) combines. Softmax WITHOUT max-subtraction
// (scores O(+-5), fp32-safe, absmax ~1e-3 since R4).
// Tail: this block's 8 sigmoid rows feed partial out[b,w,o] via atomicAdd.
__global__ __launch_bounds__(512, 4) void k_attn(
    const float* __restrict__ left, const float* __restrict__ right,
    const float* __restrict__ lin_b, const float* __restrict__ a,
    const float* __restrict__ bias_kk, const float* __restrict__ v,
    const float* __restrict__ fc_w, float* __restrict__ out) {
  const int xcd  = blockIdx.x & 7;
  const int sblk = blockIdx.x >> 3;
  const int b    = 2 * xcd + (sblk & 1);
  const int i0   = (sblk >> 1) * 8;
  const int tid  = threadIdx.x;
  const int j    = tid >> 1;    // 0..255 (score-row owner pair)
  const int eh   = tid & 1;     // e-half: [0,64) or [64,128)

  __shared__ float s_lb[8][132];    // left[b,i0+i,:] + lin_b; reused as h/fw
  __shared__ float s_a[128];
  __shared__ float s_ca[128];       // C2 * a
  __shared__ float s_AL[8];
  __shared__ float s_sc[8][260];    // exp(score) (unnormalized p)
  __shared__ float s_v[256][64];    // full v[b] panel, linear (DMA target)

  // ---- stage a / 0.4*a and left-tile (+lin_b) ----
  if (tid < 128) {
    float av = a[tid];
    s_a[tid]  = av;
    s_ca[tid] = C2 * av;
  }
  {
    const int ii = tid >> 6;          // 0..7
    const int e2 = (tid & 63) * 2;
    float2 lv = *(const float2*)(left + (b * 256 + i0 + ii) * 128 + e2);
    float2 bv = *(const float2*)(lin_b + e2);
    s_lb[ii][e2 + 0] = lv.x + bv.x;
    s_lb[ii][e2 + 1] = lv.y + bv.y;
  }
  __syncthreads();  // b1

  // ---- hoist this thread's e-half of right row j: 16 b128 loads ----
  const float4* rp = (const float4*)(right + (b * 256 + j) * 128 + eh * 64);
  float4 r[16];
#pragma unroll
  for (int q = 0; q < 16; ++q) r[q] = rp[q];

  // ---- async-stage v[b] (256x64 = 64KB) into LDS; drains at b2 ----
  {
    const int seg0 = (tid >> 6) * 8;      // wave's 8 segments (256 floats ea)
    const int ln4  = (tid & 63) * 4;
    const float* vb = v + b * 16384;
#pragma unroll
    for (int t = 0; t < 8; ++t) {
      const int seg = seg0 + t;
      gld_lds16(vb + seg * 256 + ln4, &s_v[0][0] + seg * 256);
    }
  }

  // ---- AL[i] = sum_e a_e * lb[i][e]: wave wv reduces row wv ----
  {
    const int ii = tid >> 6, sl = tid & 63;
    float p = s_a[sl * 2] * s_lb[ii][sl * 2] +
              s_a[sl * 2 + 1] * s_lb[ii][sl * 2 + 1];
#pragma unroll
    for (int off = 32; off > 0; off >>= 1) p += __shfl_xor(p, off, 64);
    if (sl == 0) s_AL[ii] = p;
  }

  // ---- scores (half-row): acc[i] += 0.4a|lb+r|, ar += a*r over 64 e's ----
  float acc[8];
#pragma unroll
  for (int i = 0; i < 8; ++i) acc[i] = 0.f;
  float ar = 0.f;
  const int eb = eh * 64;
#pragma unroll
  for (int ec = 0; ec < 4; ++ec) {
    float4 r0 = r[ec * 4 + 0], r1 = r[ec * 4 + 1],
           r2 = r[ec * 4 + 2], r3 = r[ec * 4 + 3];
    const int base = eb + ec * 16;
    float4 a0 = *(const float4*)&s_a[base + 0];
    float4 a1 = *(const float4*)&s_a[base + 4];
    float4 a2 = *(const float4*)&s_a[base + 8];
    float4 a3 = *(const float4*)&s_a[base + 12];
    ar += a0.x * r0.x + a0.y * r0.y + a0.z * r0.z + a0.w * r0.w;
    ar += a1.x * r1.x + a1.y * r1.y + a1.z * r1.z + a1.w * r1.w;
    ar += a2.x * r2.x + a2.y * r2.y + a2.z * r2.z + a2.w * r2.w;
    ar += a3.x * r3.x + a3.y * r3.y + a3.z * r3.z + a3.w * r3.w;
    float4 c0 = *(const float4*)&s_ca[base + 0];
    float4 c1 = *(const float4*)&s_ca[base + 4];
    float4 c2 = *(const float4*)&s_ca[base + 8];
    float4 c3 = *(const float4*)&s_ca[base + 12];
#pragma unroll
    for (int i = 0; i < 8; ++i) {
      float4 l0 = *(const float4*)&s_lb[i][base + 0];
      float4 l1 = *(const float4*)&s_lb[i][base + 4];
      float4 l2 = *(const float4*)&s_lb[i][base + 8];
      float4 l3 = *(const float4*)&s_lb[i][base + 12];
      float t, s = acc[i];
      t = l0.x + r0.x; s = fmaf(c0.x, fabsf(t), s);
      t = l0.y + r0.y; s = fmaf(c0.y, fabsf(t), s);
      t = l0.z + r0.z; s = fmaf(c0.z, fabsf(t), s);
      t = l0.w + r0.w; s = fmaf(c0.w, fabsf(t), s);
      t = l1.x + r1.x; s = fmaf(c1.x, fabsf(t), s);
      t = l1.y + r1.y; s = fmaf(c1.y, fabsf(t), s);
      t = l1.z + r1.z; s = fmaf(c1.z, fabsf(t), s);
      t = l1.w + r1.w; s = fmaf(c1.w, fabsf(t), s);
      t = l2.x + r2.x; s = fmaf(c2.x, fabsf(t), s);
      t = l2.y + r2.y; s = fmaf(c2.y, fabsf(t), s);
      t = l2.z + r2.z; s = fmaf(c2.z, fabsf(t), s);
      t = l2.w + r2.w; s = fmaf(c2.w, fabsf(t), s);
      t = l3.x + r3.x; s = fmaf(c3.x, fabsf(t), s);
      t = l3.y + r3.y; s = fmaf(c3.y, fabsf(t), s);
      t = l3.z + r3.z; s = fmaf(c3.z, fabsf(t), s);
      t = l3.w + r3.w; s = fmaf(c3.w, fabsf(t), s);
      acc[i] = s;
    }
  }

  // ---- bias row loads (late: latency hidden under the b2 barrier wait) ----
  float bk[8];
#pragma unroll
  for (int i = 0; i < 8; ++i) bk[i] = bias_kk[(i0 + i) * 256 + j];

  __syncthreads();  // b2 (s_AL visible; v DMA drained by implicit vmcnt(0))

  // ---- combine e-halves across the lane pair ----
#pragma unroll
  for (int i = 0; i < 8; ++i) acc[i] += __shfl_xor(acc[i], 1, 64);
  ar += __shfl_xor(ar, 1, 64);

  // ---- finalize + exp, even lane of each pair writes p ----
#pragma unroll
  for (int i = 0; i < 8; ++i) {
    float sc = fmaf(C1, s_AL[i] + ar, acc[i]) + bk[i];
    float p = __expf(sc);
    if (eh == 0) s_sc[i][j] = p;
  }
  __syncthreads();  // b3

  // ---- fc_w tile loads issued NOW; consumed after PV (latency hidden) ----
  const int fo = tid >> 3, fi = tid & 7;      // tile: 64 o x 8 i
  float fwv = fc_w[fo * 256 + i0 + fi];

  // ---- row sum: wave wv reduces row wv (the row it consumes in PV);
  //      64-lane butterfly leaves 1/sum in every lane's register ----
  float inv;
  {
    const int wv = tid >> 6, lane = tid & 63;
    float ssum = s_sc[wv][lane] + s_sc[wv][lane + 64] +
                 s_sc[wv][lane + 128] + s_sc[wv][lane + 192];
#pragma unroll
    for (int off = 32; off > 0; off >>= 1) ssum += __shfl_xor(ssum, off, 64);
    inv = 1.f / ssum;
  }

  // ---- h[i,w] = sigmoid( (sum_j p_j * v[j,w]) * inv ), all from LDS.
  //      Pair split over j-halves: q = tid>>1 -> (iq = q>>5, wp = q&31),
  //      jh = tid&1 covers j in [jh*128, jh*128+128). ----
  const int iq = tid >> 6;              // == wave id == row
  const int wp = (tid >> 1) & 31;
  const int jh = tid & 1;
  const int w  = wp * 2;
  float h0 = 0.f, h1 = 0.f;
  const int jbase = jh * 128;
#pragma unroll 4
  for (int jj = 0; jj < 128; jj += 4) {
    float4 at = *(const float4*)&s_sc[iq][jbase + jj];
    float2 v0 = *(const float2*)&s_v[jbase + jj + 0][w];
    float2 v1 = *(const float2*)&s_v[jbase + jj + 1][w];
    float2 v2 = *(const float2*)&s_v[jbase + jj + 2][w];
    float2 v3 = *(const float2*)&s_v[jbase + jj + 3][w];
    h0 += at.x * v0.x + at.y * v1.x + at.z * v2.x + at.w * v3.x;
    h1 += at.x * v0.y + at.y * v1.y + at.z * v2.y + at.w * v3.y;
  }
  h0 += __shfl_xor(h0, 1, 64);
  h1 += __shfl_xor(h1, 1, 64);

  // ---- overlay dead s_lb: s_h = sigmoid tile [8][64], s_fw = fc_w tile ----
  float* s_h  = &s_lb[0][0];          // 512 floats
  float* s_fw = &s_lb[0][0] + 512;    // 512 floats (1056 available)
  if (jh == 0) {
    s_h[iq * 64 + w + 0] = 1.f / (1.f + __expf(-h0 * inv));
    s_h[iq * 64 + w + 1] = 1.f / (1.f + __expf(-h1 * inv));
  }
  s_fw[fi * 64 + fo] = fwv;
  __syncthreads();  // b4

  // ---- fused k_out partial: out[b,w,o] += sum_i s_h[i][w] * fc_w[o,i0+i].
  //      thread = (o = tid&63, wset = tid>>6); 8 w's each; coalesced atomics.
  {
    const int o   = tid & 63;
    const int ws8 = (tid >> 6) * 8;
    float av[8] = {0, 0, 0, 0, 0, 0, 0, 0};
#pragma unroll
    for (int i = 0; i < 8; ++i) {
      float fwi = s_fw[i * 64 + o];           // lanes o-consecutive: no conflict
#pragma unroll
      for (int ww = 0; ww < 8; ++ww)          // s_h read is wave-uniform: broadcast
        av[ww] = fmaf(fwi, s_h[i * 64 + ws8 + ww], av[ww]);
    }
#pragma unroll
    for (int ww = 0; ww < 8; ++ww)
      atomicAdd(&out[b * 4096 + (ws8 + ww) * 64 + o], av[ww]);
  }
}

extern "C" void kernel_launch(void* const* d_in, const int* in_sizes, int n_in,
                              void* d_out, int out_size, void* d_ws, size_t ws_size,
                              hipStream_t stream) {
  const float* x       = (const float*)d_in[0];
  const float* lin_w   = (const float*)d_in[1];
  const float* lin_b   = (const float*)d_in[2];
  const float* a       = (const float*)d_in[3];
  const float* bias_kk = (const float*)d_in[4];
  const float* fc_w    = (const float*)d_in[5];
  const float* fc_b    = (const float*)d_in[6];
  float* out = (float*)d_out;

  float* ws    = (float*)d_ws;
  float* left  = ws;                // 16*256*128 = 524288
  float* right = ws + 524288;       // 524288
  float* v     = ws + 1048576;      // 16*256*64 = 262144

  k_proj<<<512, 256, 0, stream>>>(x, lin_w, fc_b, left, right, v, out);
  k_attn<<<512, 512, 0, stream>>>(left, right, lin_b, a, bias_kk, v, fc_w, out);
}